// Round 1
// baseline (175.534 us; speedup 1.0000x reference)
//
#include <hip/hip_runtime.h>
#include <math.h>

#define P 8
#define Q 24
#define N 32
#define TT 64

// ---------------------------------------------------------------------------
// prep_yb: compute yb = cayley(tangent_vector(question_bias)) (32x32) into ws.
// Bias entries are O(1) so (I + xb xb^T)^{-1} is computed EXACTLY via
// parallel Gauss-Jordan on the 8x8 (SPD, pivots >= 1, no pivoting needed).
// Cayley block form: yb = [[2M-I, -2H],[2H^T, I - 2 xb^T H]], H = M xb.
// ---------------------------------------------------------------------------
__global__ __launch_bounds__(64) void prep_yb(const float* __restrict__ qbias,
                                              float* __restrict__ yb_out) {
    __shared__ float xb[P * Q];     // 8x24
    __shared__ float Aug[P][16];    // [A | I] augmented
    __shared__ float H[P * Q];      // M * xb (8x24)
    const int ln = threadIdx.x;
    xb[ln] = qbias[ln];
    xb[ln + 64] = qbias[ln + 64];
    xb[ln + 128] = qbias[ln + 128];
    __syncthreads();

    const int i = ln >> 3, j = ln & 7;
    // A = I + xb xb^T
    float a = (i == j) ? 1.0f : 0.0f;
    for (int k = 0; k < Q; ++k) a += xb[i * Q + k] * xb[j * Q + k];
    Aug[i][j] = a;
    Aug[i][j + 8] = (i == j) ? 1.0f : 0.0f;
    __syncthreads();

    // Gauss-Jordan (exact inverse)
    for (int k = 0; k < P; ++k) {
        const float piv = Aug[k][k];
        __syncthreads();                      // all reads of pivot before write
        if (i == k) {
            const float ip = 1.0f / piv;
            Aug[k][j] *= ip;
            Aug[k][j + 8] *= ip;
        }
        __syncthreads();
        const float f = Aug[i][k];
        __syncthreads();                      // read factors before elimination
        if (i != k) {
            Aug[i][j]     -= f * Aug[k][j];
            Aug[i][j + 8] -= f * Aug[k][j + 8];
        }
        __syncthreads();
    }

    // H = M * xb  (8x24)
    for (int idx = ln; idx < P * Q; idx += 64) {
        const int r = idx / Q, c = idx % Q;
        float h = 0.0f;
        for (int m = 0; m < P; ++m) h += Aug[r][8 + m] * xb[m * Q + c];
        H[idx] = h;
    }
    __syncthreads();

    // yb (32x32)
    for (int idx = ln; idx < N * N; idx += 64) {
        const int r = idx >> 5, c = idx & 31;
        float v;
        if (r < P && c < P) {
            v = 2.0f * Aug[r][8 + c] - ((r == c) ? 1.0f : 0.0f);
        } else if (r < P) {
            v = -2.0f * H[r * Q + (c - P)];
        } else if (c < P) {
            v = 2.0f * H[c * Q + (r - P)];
        } else {
            float s2 = 0.0f;
            for (int m = 0; m < P; ++m) s2 += xb[m * Q + (r - P)] * H[m * Q + (c - P)];
            v = ((r == c) ? 1.0f : 0.0f) - 2.0f * s2;
        }
        yb_out[idx] = v;
    }
}

// ---------------------------------------------------------------------------
// chains: one block per batch b. Wave 0 = question chain, wave 1 = answer
// chain. State U (32x8) = first 8 cols of the running right-to-left product;
// per step:  W = Up - x Uq;  G = 2 (I - E + E^2) W  (E = x x^T, ||E||~6e-5);
//            Up' = G - Up;  Uq' = x^T G + Uq.
// Then (q side) U <- yb U, join: dist = || Uq Uq^T - V V^T ||_F.
// ---------------------------------------------------------------------------
__global__ __launch_bounds__(128) void chains(
    const int* __restrict__ s1, const int* __restrict__ s2,
    const float* __restrict__ qemb, const float* __restrict__ aemb,
    const float* __restrict__ qtr, const float* __restrict__ ybg,
    const float* __restrict__ wf, const float* __restrict__ wb,
    float* __restrict__ out) {
    __shared__ float x[2][P * Q];
    __shared__ float U[2][N][P];
    __shared__ float Em[2][64], Wm[2][64], Tm[2][64], Gm[2][64];
    __shared__ float ybs[N * N];
    __shared__ float red[128];

    const int tid = threadIdx.x;
    const int s = tid >> 6;       // side: 0 = question, 1 = answer
    const int ln = tid & 63;
    const int b = blockIdx.x;
    const int i8 = ln >> 3, j8 = ln & 7;

    for (int idx = tid; idx < N * N; idx += 128) ybs[idx] = ybg[idx];

    // U = [I8 ; 0]
    for (int idx = ln; idx < N * P; idx += 64) {
        const int r = idx >> 3, c = idx & 7;
        U[s][r][c] = (r == c) ? 1.0f : 0.0f;
    }

    const int* sent = s ? s2 : s1;
    const float* emb = s ? aemb : qemb;
    const int myid = sent[b * TT + ln];   // lane t holds token id of step t
    float tr0, tr1, tr2;
    if (s == 0) { tr0 = qtr[ln]; tr1 = qtr[ln + 64]; tr2 = qtr[ln + 128]; }
    else        { tr0 = 1.0f; tr1 = 1.0f; tr2 = 1.0f; }

    // prefetch step T-1 embedding (3 floats/lane)
    {
        const int id = __shfl(myid, TT - 1);
        const size_t base = (size_t)id * (P * Q);
        // fallthrough into loop with e regs loaded
        float e0 = emb[base + ln], e1 = emb[base + 64 + ln], e2 = emb[base + 128 + ln];

        for (int t = TT - 1; t >= 0; --t) {
            // stage x = tok (8x24) into LDS
            x[s][ln]       = e0 * tr0;
            x[s][ln + 64]  = e1 * tr1;
            x[s][ln + 128] = e2 * tr2;
            if (t > 0) {   // prefetch next step's embedding (overlaps compute)
                const int idn = __shfl(myid, t - 1);
                const size_t bs = (size_t)idn * (P * Q);
                e0 = emb[bs + ln];
                e1 = emb[bs + 64 + ln];
                e2 = emb[bs + 128 + ln];
            }
            __syncthreads();

            // E = x x^T, W = Up - x Uq   (lane -> (i8, j8))
            float eacc = 0.0f, wacc = U[s][i8][j8];
            for (int k = 0; k < Q; ++k) {
                const float xa = x[s][i8 * Q + k];
                eacc += xa * x[s][j8 * Q + k];
                wacc -= xa * U[s][P + k][j8];
            }
            Em[s][ln] = eacc;
            Wm[s][ln] = wacc;
            __syncthreads();

            // T = W - E W
            float tacc = Wm[s][ln];
            for (int m = 0; m < P; ++m) tacc -= Em[s][i8 * P + m] * Wm[s][m * P + j8];
            Tm[s][ln] = tacc;
            __syncthreads();

            // G = 2 (W - E T) = 2 (I - E + E^2) W
            float gacc = Wm[s][ln];
            for (int m = 0; m < P; ++m) gacc -= Em[s][i8 * P + m] * Tm[s][m * P + j8];
            gacc *= 2.0f;
            Gm[s][ln] = gacc;
            __syncthreads();

            // Up' = G - Up ; Uq' = x^T G + Uq
            U[s][i8][j8] = gacc - U[s][i8][j8];
            for (int idx = ln; idx < Q * P; idx += 64) {
                const int k = idx >> 3, j = idx & 7;
                float u = U[s][P + k][j];
                for (int m = 0; m < P; ++m) u += x[s][m * Q + k] * Gm[s][m * P + j];
                U[s][P + k][j] = u;
            }
            __syncthreads();
        }
    }

    // question side: U <- yb U  (32x8, 4 entries per lane of wave 0)
    float nv[4];
    if (s == 0) {
        for (int r4 = 0; r4 < 4; ++r4) {
            const int idx = ln + r4 * 64;
            const int r = idx >> 3, c = idx & 7;
            float acc = 0.0f;
            for (int m = 0; m < N; ++m) acc += ybs[r * N + m] * U[0][m][c];
            nv[r4] = acc;
        }
    }
    __syncthreads();
    if (s == 0) {
        for (int r4 = 0; r4 < 4; ++r4) {
            const int idx = ln + r4 * 64;
            U[0][idx >> 3][idx & 7] = nv[r4];
        }
    }
    __syncthreads();

    // dist^2 = sum over 32x32 of (U0 U0^T - U1 U1^T)^2
    float acc = 0.0f;
    for (int idx = tid; idx < N * N; idx += 128) {
        const int r = idx >> 5, c = idx & 31;
        float p = 0.0f;
        for (int j = 0; j < P; ++j)
            p += U[0][r][j] * U[0][c][j] - U[1][r][j] * U[1][c][j];
        acc += p * p;
    }
    red[tid] = acc;
    __syncthreads();
    if (tid == 0) {
        float ssum = 0.0f;
        for (int u2 = 0; u2 < 128; ++u2) ssum += red[u2];
        out[b] = -wf[0] * sqrtf(ssum) + wb[0];
    }
}

extern "C" void kernel_launch(void* const* d_in, const int* in_sizes, int n_in,
                              void* d_out, int out_size, void* d_ws, size_t ws_size,
                              hipStream_t stream) {
    const int* s1 = (const int*)d_in[0];
    const int* s2 = (const int*)d_in[1];
    const float* qemb  = (const float*)d_in[2];
    const float* aemb  = (const float*)d_in[3];
    const float* qtr   = (const float*)d_in[4];
    const float* qbias = (const float*)d_in[5];
    const float* wf    = (const float*)d_in[6];
    const float* wb    = (const float*)d_in[7];
    float* out = (float*)d_out;
    float* yb = (float*)d_ws;   // 1024 floats

    prep_yb<<<1, 64, 0, stream>>>(qbias, yb);
    chains<<<512, 128, 0, stream>>>(s1, s2, qemb, aemb, qtr, yb, wf, wb, out);
}

// Round 2
// 143.139 us; speedup vs baseline: 1.2263x; 1.2263x over previous
//
#include <hip/hip_runtime.h>
#include <math.h>

#define TT 64

// wave-local LDS fence: waitcnt lgkmcnt(0) ONLY (vmcnt untouched -> global
// prefetch stays in flight). wave_barrier pins compiler ordering.
__device__ __forceinline__ void syncwave() {
    __builtin_amdgcn_wave_barrier();
    __builtin_amdgcn_s_waitcnt(0xC07F);   // vmcnt=63(no wait), expcnt=7, lgkmcnt=0
    __builtin_amdgcn_wave_barrier();
}

template<int OFF>
__device__ __forceinline__ float swz(float v) {
    return __int_as_float(__builtin_amdgcn_ds_swizzle(__float_as_int(v), OFF));
}
// ds_swizzle BitMode offset = (xor<<10)|(or<<5)|and ; groups of 8 within 32-lane half.
// broadcast lane (group8 | M): and=0b11000=24, or=M  -> OFF = (M<<5)|24
#define BC8ALL(dst, src)                                            \
    dst[0] = swz<24>(src);  dst[1] = swz<56>(src);                  \
    dst[2] = swz<88>(src);  dst[3] = swz<120>(src);                 \
    dst[4] = swz<152>(src); dst[5] = swz<184>(src);                 \
    dst[6] = swz<216>(src); dst[7] = swz<248>(src);

// ---------------------------------------------------------------------------
// prep_yb: yb = cayley(tangent_vector(question_bias)) (32x32) into ws.
// Exact 8x8 Gauss-Jordan (bias is O(1), Neumann won't converge).
// ---------------------------------------------------------------------------
__global__ __launch_bounds__(64) void prep_yb(const float* __restrict__ qbias,
                                              float* __restrict__ yb_out) {
    __shared__ float xb[8 * 24];
    __shared__ float Aug[8][16];
    __shared__ float H[8 * 24];
    const int ln = threadIdx.x;
    xb[ln] = qbias[ln];
    xb[ln + 64] = qbias[ln + 64];
    xb[ln + 128] = qbias[ln + 128];
    __syncthreads();

    const int i = ln >> 3, j = ln & 7;
    float a = (i == j) ? 1.0f : 0.0f;
    for (int k = 0; k < 24; ++k) a += xb[i * 24 + k] * xb[j * 24 + k];
    Aug[i][j] = a;
    Aug[i][j + 8] = (i == j) ? 1.0f : 0.0f;
    __syncthreads();

    for (int k = 0; k < 8; ++k) {
        const float piv = Aug[k][k];
        __syncthreads();
        if (i == k) {
            const float ip = 1.0f / piv;
            Aug[k][j] *= ip;
            Aug[k][j + 8] *= ip;
        }
        __syncthreads();
        const float f = Aug[i][k];
        __syncthreads();
        if (i != k) {
            Aug[i][j]     -= f * Aug[k][j];
            Aug[i][j + 8] -= f * Aug[k][j + 8];
        }
        __syncthreads();
    }

    for (int idx = ln; idx < 8 * 24; idx += 64) {
        const int r = idx / 24, c = idx % 24;
        float h = 0.0f;
        for (int m = 0; m < 8; ++m) h += Aug[r][8 + m] * xb[m * 24 + c];
        H[idx] = h;
    }
    __syncthreads();

    for (int idx = ln; idx < 32 * 32; idx += 64) {
        const int r = idx >> 5, c = idx & 31;
        float v;
        if (r < 8 && c < 8) {
            v = 2.0f * Aug[r][8 + c] - ((r == c) ? 1.0f : 0.0f);
        } else if (r < 8) {
            v = -2.0f * H[r * 24 + (c - 8)];
        } else if (c < 8) {
            v = 2.0f * H[c * 24 + (r - 8)];
        } else {
            float s2 = 0.0f;
            for (int m = 0; m < 8; ++m) s2 += xb[m * 24 + (r - 8)] * H[m * 24 + (c - 8)];
            v = ((r == c) ? 1.0f : 0.0f) - 2.0f * s2;
        }
        yb_out[idx] = v;
    }
}

// ---------------------------------------------------------------------------
// chains: block b = batch b; wave 0 = question chain, wave 1 = answer chain.
// Lane l = 8*j + i handles column j of U. Registers: up = Up[i][j],
// uq[c] = Uq[8c+i][j], xt[c][m] = x[m][8c+i].
// Step (exact to O(X^3), X ~ 5e-3):
//   s = x^T Up ; t = x (Uq + s) ; Up' = Up - 2t ; Uq' = Uq + 2s - 2 x^T t
// LDS only transposes x (global row-major -> xT). No __syncthreads in loop.
// Distance: dist^2 = 16 - 2 || U0^T U1 ||_F^2  (columns orthonormal).
// ---------------------------------------------------------------------------
__global__ __launch_bounds__(128) void chains(
    const int* __restrict__ s1, const int* __restrict__ s2,
    const float* __restrict__ qemb, const float* __restrict__ aemb,
    const float* __restrict__ qtr, const float* __restrict__ ybg,
    const float* __restrict__ wf, const float* __restrict__ wb,
    float* __restrict__ out) {
    __shared__ __align__(16) float xbuf[2][2][192];   // [wave][parity][xT 24x8]
    __shared__ __align__(16) float ybs[1024];
    __shared__ __align__(16) float Ucm[2][8][32];     // [side][col][row]

    const int tid = threadIdx.x;
    const int s = tid >> 6;
    const int l = tid & 63;
    const int b = blockIdx.x;
    const int i = l & 7;
    const int j = l >> 3;

    if (s == 0) {   // stage yb (wave-private use, no barrier needed)
        const float4* ys = (const float4*)ybg;
        float4* yd = (float4*)ybs;
        #pragma unroll
        for (int u = 0; u < 4; ++u) yd[l + 64 * u] = ys[l + 64 * u];
    }

    const int* sent = s ? s2 : s1;
    const float* emb = s ? aemb : qemb;
    const int myid = sent[b * TT + l];

    float trv0 = 1.0f, trv1 = 1.0f, trv2 = 1.0f;
    if (s == 0) { trv0 = qtr[3 * l]; trv1 = qtr[3 * l + 1]; trv2 = qtr[3 * l + 2]; }

    // x-transpose store offsets (lane-invariant over the loop)
    const int f0 = 3 * l, f1 = 3 * l + 1, f2 = 3 * l + 2;
    const int o0 = (f0 % 24) * 8 + f0 / 24;
    const int o1 = (f1 % 24) * 8 + f1 / 24;
    const int o2 = (f2 % 24) * 8 + f2 / 24;

    float up = (i == j) ? 1.0f : 0.0f;
    float uq0 = 0.0f, uq1 = 0.0f, uq2 = 0.0f;
    float xt[3][8];

    {   // preload step 63
        const int id = __shfl(myid, TT - 1);
        const float* p = emb + (size_t)id * 192 + f0;
        float* xw = &xbuf[s][1][0];
        xw[o0] = p[0] * trv0; xw[o1] = p[1] * trv1; xw[o2] = p[2] * trv2;
        syncwave();
        const float4* xv = (const float4*)xw;
        #pragma unroll
        for (int c = 0; c < 3; ++c) {
            float4 A = xv[(8 * c + i) * 2], B = xv[(8 * c + i) * 2 + 1];
            xt[c][0] = A.x; xt[c][1] = A.y; xt[c][2] = A.z; xt[c][3] = A.w;
            xt[c][4] = B.x; xt[c][5] = B.y; xt[c][6] = B.z; xt[c][7] = B.w;
        }
    }

    const bool h4 = (i & 4) != 0, h2 = (i & 2) != 0, h1 = (i & 1) != 0;

    for (int t = TT - 1; t >= 0; --t) {
        float e0 = 0.f, e1 = 0.f, e2 = 0.f;
        if (t > 0) {   // prefetch next token's embedding (stays in flight: no vmcnt drain)
            const int id = __shfl(myid, t - 1);
            const float* p = emb + (size_t)id * 192 + f0;
            e0 = p[0]; e1 = p[1]; e2 = p[2];
        }
        // ---- s = x^T Up : broadcast Up column within the 8-group
        float ub[8];
        BC8ALL(ub, up);
        float sc[3];
        #pragma unroll
        for (int c = 0; c < 3; ++c) {
            float a0 = fmaf(xt[c][1], ub[1], xt[c][0] * ub[0]);
            float a1 = fmaf(xt[c][3], ub[3], xt[c][2] * ub[2]);
            float a2 = fmaf(xt[c][5], ub[5], xt[c][4] * ub[4]);
            float a3 = fmaf(xt[c][7], ub[7], xt[c][6] * ub[6]);
            sc[c] = (a0 + a1) + (a2 + a3);
        }
        const float v0 = uq0 + sc[0], v1 = uq1 + sc[1], v2 = uq2 + sc[2];
        // ---- t = x (Uq + s): per-lane partials, hypercube reduce-scatter over 8
        float Pm[8];
        #pragma unroll
        for (int m = 0; m < 8; ++m)
            Pm[m] = fmaf(xt[0][m], v0, fmaf(xt[1][m], v1, xt[2][m] * v2));
        float q0, q1, q2, q3;
        {   // xor-4 : OFF = (4<<10)|31 = 4127
            float ow, sd;
            ow = h4 ? Pm[4] : Pm[0]; sd = h4 ? Pm[0] : Pm[4]; q0 = ow + swz<4127>(sd);
            ow = h4 ? Pm[5] : Pm[1]; sd = h4 ? Pm[1] : Pm[5]; q1 = ow + swz<4127>(sd);
            ow = h4 ? Pm[6] : Pm[2]; sd = h4 ? Pm[2] : Pm[6]; q2 = ow + swz<4127>(sd);
            ow = h4 ? Pm[7] : Pm[3]; sd = h4 ? Pm[3] : Pm[7]; q3 = ow + swz<4127>(sd);
        }
        float r0, r1;
        {   // xor-2 : 2079
            float ow, sd;
            ow = h2 ? q2 : q0; sd = h2 ? q0 : q2; r0 = ow + swz<2079>(sd);
            ow = h2 ? q3 : q1; sd = h2 ? q1 : q3; r1 = ow + swz<2079>(sd);
        }
        float ttv;
        {   // xor-1 : 1055
            float ow = h1 ? r1 : r0, sd = h1 ? r0 : r1;
            ttv = ow + swz<1055>(sd);
        }
        up = fmaf(-2.0f, ttv, up);
        // ---- Uq' = Uq + 2s - 2 x^T t : broadcast t
        float tb[8];
        BC8ALL(tb, ttv);
        #pragma unroll
        for (int c = 0; c < 3; ++c) {
            float a0 = fmaf(xt[c][1], tb[1], xt[c][0] * tb[0]);
            float a1 = fmaf(xt[c][3], tb[3], xt[c][2] * tb[2]);
            float a2 = fmaf(xt[c][5], tb[5], xt[c][4] * tb[4]);
            float a3 = fmaf(xt[c][7], tb[7], xt[c][6] * tb[6]);
            float ac = (a0 + a1) + (a2 + a3);
            float ds2 = 2.0f * (sc[c] - ac);
            if (c == 0) uq0 += ds2; else if (c == 1) uq1 += ds2; else uq2 += ds2;
        }
        if (t > 0) {   // stage x for step t-1 (double buffer), reload xt regs
            float* xw = &xbuf[s][(t - 1) & 1][0];
            xw[o0] = e0 * trv0; xw[o1] = e1 * trv1; xw[o2] = e2 * trv2;
            syncwave();
            const float4* xv = (const float4*)xw;
            #pragma unroll
            for (int c = 0; c < 3; ++c) {
                float4 A = xv[(8 * c + i) * 2], B = xv[(8 * c + i) * 2 + 1];
                xt[c][0] = A.x; xt[c][1] = A.y; xt[c][2] = A.z; xt[c][3] = A.w;
                xt[c][4] = B.x; xt[c][5] = B.y; xt[c][6] = B.z; xt[c][7] = B.w;
            }
        }
    }

    // ---- epilogue: q-side applies yb (U <- yb * U), column j stays in-group
    if (s == 0) {
        float Ub[32];
        BC8ALL(Ub, up);
        { float* d = Ub + 8;  BC8ALL(d, uq0); }
        { float* d = Ub + 16; BC8ALL(d, uq1); }
        { float* d = Ub + 24; BC8ALL(d, uq2); }
        float nu[4];
        #pragma unroll
        for (int c4 = 0; c4 < 4; ++c4) {
            const int r = i + 8 * c4;
            const float* yr = &ybs[r * 32];
            float acc = 0.0f;
            #pragma unroll
            for (int m = 0; m < 32; ++m) acc = fmaf(yr[m], Ub[m], acc);
            nu[c4] = acc;
        }
        up = nu[0]; uq0 = nu[1]; uq1 = nu[2]; uq2 = nu[3];
    }

    // write U column-major for the join
    Ucm[s][j][i]      = up;
    Ucm[s][j][8 + i]  = uq0;
    Ucm[s][j][16 + i] = uq1;
    Ucm[s][j][24 + i] = uq2;
    __syncthreads();

    if (s == 0) {
        const int a = l >> 3, bb = l & 7;   // M[a][b] = <U0 col a, U1 col b>
        const float4* ca = (const float4*)&Ucm[0][a][0];
        const float4* cb = (const float4*)&Ucm[1][bb][0];
        float acc = 0.0f;
        #pragma unroll
        for (int u = 0; u < 8; ++u) {
            float4 A = ca[u], B = cb[u];
            acc += A.x * B.x + A.y * B.y + A.z * B.z + A.w * B.w;
        }
        float val = acc * acc;
        #pragma unroll
        for (int d = 1; d < 64; d <<= 1) val += __shfl_xor(val, d);
        if (l == 0) {
            const float d2 = 16.0f - 2.0f * val;
            out[b] = -wf[0] * sqrtf(fmaxf(d2, 0.0f)) + wb[0];
        }
    }
}

extern "C" void kernel_launch(void* const* d_in, const int* in_sizes, int n_in,
                              void* d_out, int out_size, void* d_ws, size_t ws_size,
                              hipStream_t stream) {
    const int* s1 = (const int*)d_in[0];
    const int* s2 = (const int*)d_in[1];
    const float* qemb  = (const float*)d_in[2];
    const float* aemb  = (const float*)d_in[3];
    const float* qtr   = (const float*)d_in[4];
    const float* qbias = (const float*)d_in[5];
    const float* wf    = (const float*)d_in[6];
    const float* wb    = (const float*)d_in[7];
    float* out = (float*)d_out;
    float* yb = (float*)d_ws;   // 1024 floats

    prep_yb<<<1, 64, 0, stream>>>(qbias, yb);
    chains<<<512, 128, 0, stream>>>(s1, s2, qemb, aemb, qtr, yb, wf, wb, out);
}